// Round 8
// baseline (161.046 us; speedup 1.0000x reference)
//
#include <hip/hip_runtime.h>
#include <math.h>

// PointLaplacianLoss — grid-pruned exact KNN, round 8.
//
// Round-7 lesson: per-lane neighborhood walk = ~85 divergent 64-lane gathers
// per wave at 2 waves/SIMD -> ~33 us of exposed VMEM latency. Fix: waves hold
// 64 CONSECUTIVE cell-sorted queries, so their neighborhoods overlap almost
// entirely. If a block's queries span <=2 (cy,cz) rows with x-span<=6, scan
// the union rectangle(s) with WAVE-UNIFORM candidate indices (st[] bounds ->
// s_load, W[j] -> broadcast; 8-way wave slicing kept via j=j0+wv,+=8).
// Two-group overlap handled by per-row window merging (a candidate is never
// scanned twice -- duplicate keys would corrupt the top-10). Sparse blocks
// fall back to the round-7 per-lane gather path; uniform-path lanes that fail
// the s=1 coverage bound go to phase2 (exact regardless).
// Also: scan+scatter fused (one fewer dispatch); out/nfail zeroed in pack_bin.

constexpr int NPTS  = 8192;
constexpr int NB    = 2;
constexpr int KNN   = 10;
constexpr int QPB   = 64;
constexpr int WPB   = 8;
constexpr int BLOCK = QPB * WPB;        // 512
constexpr int MASK13 = 0xFFFFE000;

constexpr int   G    = 32;
constexpr int   NC   = G * G * G;
constexpr float BMIN = -5.5f;
constexpr float BW   = 11.0f;
constexpr float H    = BW / G;          // 0.34375
constexpr float INVH = (float)G / BW;

__device__ __forceinline__ int iabs(int v) { return v < 0 ? -v : v; }

// ---------------- selection helpers ----------------
__device__ __forceinline__ void ins1(int l[KNN], int x) {
#pragma unroll
    for (int k = KNN - 1; k > 0; --k) l[k] = min(l[k], max(l[k - 1], x));
    l[0] = min(l[0], x);
}
__device__ __forceinline__ void ins2(int l[KNN], int a, int b) {
    const int b0 = min(a, b), b1 = max(a, b);
#pragma unroll
    for (int k = KNN - 1; k >= 2; --k)
        l[k] = min(l[k], min(max(l[k - 1], b0), max(l[k - 2], b1)));
    l[1] = min(l[1], min(max(l[0], b0), b1));
    l[0] = min(l[0], b0);
}
template<int S>
__device__ __forceinline__ void ins2s(int l[KNN], int a, int b) {
    const int b0 = min(a, b), b1 = max(a, b);
#pragma unroll
    for (int k = KNN - 1; k >= S + 2; --k)
        l[k] = min(l[k], min(max(l[k - 1], b0), max(l[k - 2], b1)));
    l[S + 1] = min(l[S + 1], min(max(l[S], b0), b1));
    l[S] = min(l[S], b0);
}
__device__ __forceinline__ void merge_sorted(int l[KNN], const int p[KNN]) {
    ins2s<0>(l, p[0], p[1]);
    ins2s<2>(l, p[2], p[3]);
    ins2s<4>(l, p[4], p[5]);
    ins2s<6>(l, p[6], p[7]);
    ins2s<8>(l, p[8], p[9]);
}

// ---------------- build kernels ----------------
__global__ void pack_bin(const float* __restrict__ p1, float4* __restrict__ w,
                         int* __restrict__ hist, int* __restrict__ cellof,
                         float* __restrict__ out, int* __restrict__ nfail) {
    const int i = blockIdx.x * blockDim.x + threadIdx.x;
    if (i >= NB * NPTS) return;
    if (i == 0) { out[0] = 0.0f; nfail[0] = 0; }
    const float x = p1[3 * i], y = p1[3 * i + 1], z = p1[3 * i + 2];
    w[i] = make_float4(x, y, z, fmaf(x, x, fmaf(y, y, z * z)));
    const int cx = min(max((int)floorf((x - BMIN) * INVH), 0), G - 1);
    const int cy = min(max((int)floorf((y - BMIN) * INVH), 0), G - 1);
    const int cz = min(max((int)floorf((z - BMIN) * INVH), 0), G - 1);
    const int c = (cz << 10) | (cy << 5) | cx;
    cellof[i] = c;
    atomicAdd(&hist[(i >> 13) * NC + c], 1);
}

// fused exclusive scan (per-batch block) + scatter of that batch's points
__global__ __launch_bounds__(1024)
void scan_scatter(int* hist, int* starts, const int* cellof,
                  const float4* w, const float* p2,
                  float4* wsorted, float4* p2s) {
    __shared__ int wsum[16];
    const int b = blockIdx.x, t = threadIdx.x;
    const int* hb = hist + b * NC;
    int* sb = starts + b * (NC + 1);
    const int c0 = t * 32;
    int loc[32]; int sum = 0;
#pragma unroll
    for (int j = 0; j < 32; ++j) { loc[j] = hb[c0 + j]; sum += loc[j]; }
    const int lane = t & 63, wvi = t >> 6;
    int incl = sum;
#pragma unroll
    for (int off = 1; off < 64; off <<= 1) {
        const int v = __shfl_up(incl, off);
        if (lane >= off) incl += v;
    }
    if (lane == 63) wsum[wvi] = incl;
    __syncthreads();
    if (t < 16) {
        const int v = wsum[t];
        int iv = v;
#pragma unroll
        for (int off = 1; off < 16; off <<= 1) {
            const int u = __shfl_up(iv, off);
            if (t >= off) iv += u;
        }
        wsum[t] = iv - v;
    }
    __syncthreads();
    int run = wsum[wvi] + incl - sum;
#pragma unroll
    for (int j = 0; j < 32; ++j) { sb[c0 + j] = run; run += loc[j]; }
    if (t == 1023) sb[NC] = run;
    __syncthreads();                       // starts visible block-wide
    // scatter this batch's 8192 points
#pragma unroll
    for (int k = 0; k < NPTS / 1024; ++k) {
        const int i = b * NPTS + k * 1024 + t;
        const int c = cellof[i];
        const int old = atomicSub(&hist[b * NC + c], 1);
        const int pos = b * NPTS + sb[c] + old - 1;
        wsorted[pos] = w[i];
        p2s[pos] = make_float4(p2[3 * i], p2[3 * i + 1], p2[3 * i + 2], 0.0f);
    }
}

// ---------------- phase 1 ----------------
__global__ __launch_bounds__(BLOCK)
void phase1(const float4* __restrict__ wsorted, const float4* __restrict__ p2s,
            const int* __restrict__ starts, float* __restrict__ out,
            int* __restrict__ nfail, int* __restrict__ worklist)
{
    __shared__ int mv[WPB * KNN * QPB];      // 20 KB

    const int batch = blockIdx.x >> 7;
    const int lane  = threadIdx.x & 63;
    const int wv    = __builtin_amdgcn_readfirstlane(threadIdx.x >> 6);
    const int qpos  = ((blockIdx.x & 127) << 6) + lane;

    const float4* W  = wsorted + batch * NPTS;
    const float4* P2 = p2s + batch * NPTS;
    const int*    st = starts + batch * (NC + 1);

    const float4 qp = W[qpos];
    const int cx = min(max((int)floorf((qp.x - BMIN) * INVH), 0), G - 1);
    const int cy = min(max((int)floorf((qp.y - BMIN) * INVH), 0), G - 1);
    const int cz = min(max((int)floorf((qp.z - BMIN) * INVH), 0), G - 1);
    const float lox = BMIN + cx * H, loy = BMIN + cy * H, loz = BMIN + cz * H;
    const float df = fminf(fminf(fminf(qp.x - lox, lox + H - qp.x),
                                 fminf(qp.y - loy, loy + H - qp.y)),
                           fminf(qp.z - loz, loz + H - qp.z));
    const float m2x = -2.0f * qp.x, m2y = -2.0f * qp.y, m2z = -2.0f * qp.z;
    const float q2 = qp.w;
    const int IMAX = 0x7FFFFFFF;

    int l[KNN];
#pragma unroll
    for (int k = 0; k < KNN; ++k) l[k] = IMAX;
    int sCov = 1;

    // ---- block-uniform group analysis (every wave sees identical lanes) ----
    const int rowid = (cz << 5) | cy;
    int rmin = rowid, rmax = rowid;
#pragma unroll
    for (int off = 32; off >= 1; off >>= 1) {
        rmin = min(rmin, __shfl_xor(rmin, off));
        rmax = max(rmax, __shfl_xor(rmax, off));
    }
    bool two = false;
    bool uni = (rmax == rmin);
    if (!uni) {
        const unsigned long long m0 = __ballot(rowid == rmin);
        const unsigned long long m1 = __ballot(rowid == rmax);
        if ((m0 | m1) == 0xFFFFFFFFFFFFFFFFull) { uni = true; two = true; }
    }
    if (uni) {
        int x0mn = (rowid == rmin) ? cx : 999;
        int x0mx = (rowid == rmin) ? cx : -999;
        int x1mn = (rowid == rmax) ? cx : 999;
        int x1mx = (rowid == rmax) ? cx : -999;
#pragma unroll
        for (int off = 32; off >= 1; off >>= 1) {
            x0mn = min(x0mn, __shfl_xor(x0mn, off));
            x0mx = max(x0mx, __shfl_xor(x0mx, off));
            x1mn = min(x1mn, __shfl_xor(x1mn, off));
            x1mx = max(x1mx, __shfl_xor(x1mx, off));
        }
        if (x0mx - x0mn > 6 || (two && (x1mx - x1mn > 6))) uni = false;
        if (uni) {
            const int gy0 = __builtin_amdgcn_readfirstlane(rmin & 31);
            const int gz0 = __builtin_amdgcn_readfirstlane(rmin >> 5);
            const int gy1 = __builtin_amdgcn_readfirstlane(rmax & 31);
            const int gz1 = __builtin_amdgcn_readfirstlane(rmax >> 5);
            const int w0lo = __builtin_amdgcn_readfirstlane(max(x0mn - 1, 0));
            const int w0hi = __builtin_amdgcn_readfirstlane(min(x0mx + 1, G - 1));
            const int w1lo = __builtin_amdgcn_readfirstlane(max(x1mn - 1, 0));
            const int w1hi = __builtin_amdgcn_readfirstlane(min(x1mx + 1, G - 1));
            const int ng = two ? 2 : 1;
            for (int g = 0; g < ng; ++g) {
                const int gy = g ? gy1 : gy0, gz = g ? gz1 : gz0;
                const int oy = g ? gy0 : gy1, oz = g ? gz0 : gz1;
#pragma unroll
                for (int dz = -1; dz <= 1; ++dz)
#pragma unroll
                for (int dy = -1; dy <= 1; ++dy) {
                    const int ay = gy + dy, az = gz + dz;
                    if ((unsigned)ay >= G || (unsigned)az >= G) continue;
                    const bool cOther = two && (iabs(ay - oy) <= 1) &&
                                               (iabs(az - oz) <= 1);
                    if (g == 1 && cOther) continue;     // scanned in g0 (merged)
                    int xlo = g ? w1lo : w0lo;
                    int xhi = g ? w1hi : w0hi;
                    if (g == 0 && cOther) { xlo = min(xlo, w1lo); xhi = max(xhi, w1hi); }
                    const int cbase = (az << 10) | (ay << 5);
                    const int j0 = __builtin_amdgcn_readfirstlane(st[cbase + xlo]);
                    const int j1 = __builtin_amdgcn_readfirstlane(st[cbase + xhi + 1]);
                    int j = j0 + wv;
                    for (; j + WPB < j1; j += 2 * WPB) {      // wave-uniform j
                        const float4 ca = W[j];
                        const float4 cb = W[j + WPB];
                        const float da = fmaf(m2x, ca.x, fmaf(m2y, ca.y,
                                         fmaf(m2z, ca.z, ca.w + q2)));
                        const float db = fmaf(m2x, cb.x, fmaf(m2y, cb.y,
                                         fmaf(m2z, cb.z, cb.w + q2)));
                        int ka = (__float_as_int(da) & MASK13) | j;
                        int kb = (__float_as_int(db) & MASK13) | (j + WPB);
                        ka = (j == qpos) ? IMAX : ka;
                        kb = (j + WPB == qpos) ? IMAX : kb;
                        ins2(l, ka, kb);
                    }
                    if (j < j1) {
                        const float4 ca = W[j];
                        const float da = fmaf(m2x, ca.x, fmaf(m2y, ca.y,
                                         fmaf(m2z, ca.z, ca.w + q2)));
                        int ka = (__float_as_int(da) & MASK13) | j;
                        ka = (j == qpos) ? IMAX : ka;
                        ins1(l, ka);
                    }
                }
            }
        }
    }
    if (!uni) {
        // ---- round-7 per-lane adaptive gather fallback ----
        sCov = (q2 > 4.8f) ? 2 : 1;
        const int runs = (sCov == 1) ? 9 : 25;
        for (int r = 0; r < 25; ++r) {
            if (!__any(r < runs)) break;
            if (r < runs) {
                int dz3 = (r * 86) >> 8;
                const int dy3 = r - 3 * dz3 - 1;  dz3 -= 1;
                int dz5 = (r * 52429) >> 18;
                const int dy5 = r - 5 * dz5 - 2;  dz5 -= 2;
                const int dy = (sCov == 1) ? dy3 : dy5;
                const int dz = (sCov == 1) ? dz3 : dz5;
                const int ay = cy + dy, az = cz + dz;
                int j0 = 0, j1 = 0;
                if ((unsigned)ay < G && (unsigned)az < G) {
                    const int cbase = (az << 10) | (ay << 5);
                    j0 = st[cbase + max(cx - sCov, 0)];
                    j1 = st[cbase + min(cx + sCov, G - 1) + 1];
                }
                int j = j0 + wv;
                if (j < j1) {
                    float4 c4 = W[j];
                    while (true) {
                        const int jn = j + WPB;
                        const bool more = jn < j1;
                        float4 nx;
                        if (more) nx = W[jn];
                        const float d2 = fmaf(m2x, c4.x, fmaf(m2y, c4.y,
                                         fmaf(m2z, c4.z, c4.w + q2)));
                        int key = (__float_as_int(d2) & MASK13) | j;
                        key = (j == qpos) ? IMAX : key;
                        ins1(l, key);
                        if (!more) break;
                        c4 = nx; j = jn;
                    }
                }
            }
        }
    }

#pragma unroll
    for (int k = 0; k < KNN; ++k) mv[(wv * KNN + k) * QPB + lane] = l[k];
    __syncthreads();

    if (threadIdx.x < QPB) {
        int M[KNN];
#pragma unroll
        for (int k = 0; k < KNN; ++k) M[k] = IMAX;
#pragma unroll
        for (int e = 0; e < WPB; ++e) {
            int p[KNN];
#pragma unroll
            for (int k = 0; k < KNN; ++k) p[k] = mv[(e * KNN + k) * QPB + lane];
            merge_sorted(M, p);
        }

        const float tau = __int_as_float(M[KNN - 1] & MASK13);
        const float R = (float)sCov * H + df;
        const bool covered = (tau <= R * R * 0.996f);
        float v = 0.0f;
        if (covered) {
            float s1x = 0, s1y = 0, s1z = 0, s2x = 0, s2y = 0, s2z = 0;
#pragma unroll
            for (int k = 0; k < KNN; ++k) {
                const int j = M[k] & (NPTS - 1);
                const float4 c4 = W[j];
                const float4 n2 = P2[j];
                s1x += c4.x; s1y += c4.y; s1z += c4.z;
                s2x += n2.x; s2y += n2.y; s2z += n2.z;
            }
            const float4 p2v = P2[qpos];
            const float dx = (s1x * 0.1f - qp.x) - (s2x * 0.1f - p2v.x);
            const float dy2 = (s1y * 0.1f - qp.y) - (s2y * 0.1f - p2v.y);
            const float dz2 = (s1z * 0.1f - qp.z) - (s2z * 0.1f - p2v.z);
            v = fabsf(dx) + fabsf(dy2) + fabsf(dz2);
        } else {
            const int wi = atomicAdd(nfail, 1);
            worklist[wi] = (batch << 16) | qpos;
        }
#pragma unroll
        for (int off = 32; off >= 1; off >>= 1) v += __shfl_down(v, off);
        if (threadIdx.x == 0)
            atomicAdd(out, v * (1.0f / (float)(NB * NPTS * 3)));
    }
}

// ---------------- phase 2: wave-per-query exact brute force ----------------
constexpr int P2BLK = 256;
constexpr int P2GRID = 512;

__global__ __launch_bounds__(P2BLK)
void phase2(const float4* __restrict__ wsorted, const float4* __restrict__ p2s,
            const int* __restrict__ nfail, const int* __restrict__ worklist,
            float* __restrict__ out)
{
    const int lane = threadIdx.x & 63;
    const int wv   = threadIdx.x >> 6;
    const int wid  = blockIdx.x * (P2BLK / 64) + wv;
    const int NW   = P2GRID * (P2BLK / 64);
    const int nf   = *nfail;
    const int IMAX = 0x7FFFFFFF;
    float acc = 0.0f;

    for (int i = wid; i < nf; i += NW) {
        const int e = worklist[i];
        const int batch = e >> 16, qpos = e & 0xFFFF;
        const float4* W  = wsorted + batch * NPTS;
        const float4* P2 = p2s + batch * NPTS;
        const float4 qp = W[qpos];
        const float m2x = -2.0f * qp.x, m2y = -2.0f * qp.y, m2z = -2.0f * qp.z;
        const float q2 = qp.w;

        int l[KNN];
#pragma unroll
        for (int k = 0; k < KNN; ++k) l[k] = IMAX;

#pragma unroll 2
        for (int it = 0; it < NPTS / 128; ++it) {
            const int ja = it * 128 + lane, jb = ja + 64;
            const float4 ca = W[ja];
            const float4 cb = W[jb];
            const float da = fmaf(m2x, ca.x, fmaf(m2y, ca.y, fmaf(m2z, ca.z, ca.w + q2)));
            const float db = fmaf(m2x, cb.x, fmaf(m2y, cb.y, fmaf(m2z, cb.z, cb.w + q2)));
            int ka = (__float_as_int(da) & MASK13) | ja;
            int kb = (__float_as_int(db) & MASK13) | jb;
            ka = (ja == qpos) ? IMAX : ka;
            kb = (jb == qpos) ? IMAX : kb;
            ins2(l, ka, kb);
        }
        for (int off = 1; off < 64; off <<= 1) {
            int p[KNN];
#pragma unroll
            for (int k = 0; k < KNN; ++k) p[k] = __shfl_xor(l[k], off);
            merge_sorted(l, p);
        }
        float s1x = 0, s1y = 0, s1z = 0, s2x = 0, s2y = 0, s2z = 0;
#pragma unroll
        for (int k = 0; k < KNN; ++k) {
            const int j = l[k] & (NPTS - 1);
            const float4 c4 = W[j];
            const float4 n2 = P2[j];
            s1x += c4.x; s1y += c4.y; s1z += c4.z;
            s2x += n2.x; s2y += n2.y; s2z += n2.z;
        }
        const float4 p2v = P2[qpos];
        const float dx = (s1x * 0.1f - qp.x) - (s2x * 0.1f - p2v.x);
        const float dy = (s1y * 0.1f - qp.y) - (s2y * 0.1f - p2v.y);
        const float dz = (s1z * 0.1f - qp.z) - (s2z * 0.1f - p2v.z);
        if (lane == 0) acc += fabsf(dx) + fabsf(dy) + fabsf(dz);
    }

    if (lane == 0 && acc != 0.0f)
        atomicAdd(out, acc * (1.0f / (float)(NB * NPTS * 3)));
}

// ---------------- round-2 fallback (O(N^2), verified) ----------------
constexpr int CHUNK = NPTS / WPB;

__global__ void prep_pack(const float* __restrict__ p, float4* __restrict__ w) {
    const int i = blockIdx.x * blockDim.x + threadIdx.x;
    if (i < NB * NPTS) {
        const float x = p[3 * i], y = p[3 * i + 1], z = p[3 * i + 2];
        w[i] = make_float4(x, y, z, fmaf(x, x, fmaf(y, y, z * z)));
    }
}

__global__ __launch_bounds__(BLOCK, 2)
void knn_lap(const float4* __restrict__ w1, const float* __restrict__ p2,
             float* __restrict__ out)
{
    __shared__ int mv[WPB * KNN * QPB];
    const int batch = blockIdx.x >> 7;
    const int qbase = (blockIdx.x & 127) << 6;
    const int lane  = threadIdx.x & 63;
    const int wv    = __builtin_amdgcn_readfirstlane(threadIdx.x >> 6);
    const int query = qbase + lane;
    const float4* Wb = w1 + batch * NPTS;
    const float4 qp = Wb[query];
    const float m2x = -2.0f * qp.x, m2y = -2.0f * qp.y, m2z = -2.0f * qp.z;
    const float q2 = qp.w;
    const int IMAX = 0x7FFFFFFF;
    int l[KNN];
#pragma unroll
    for (int k = 0; k < KNN; ++k) l[k] = IMAX;
    const int c0 = wv * CHUNK;
    const float4* cand = Wb + c0;
#pragma unroll 4
    for (int i = 0; i < CHUNK; i += 2) {
        const float4 ca = cand[i];
        const float4 cb = cand[i + 1];
        const int ja = c0 + i, jb = ja + 1;
        const float da = fmaf(m2x, ca.x, fmaf(m2y, ca.y, fmaf(m2z, ca.z, ca.w + q2)));
        const float db = fmaf(m2x, cb.x, fmaf(m2y, cb.y, fmaf(m2z, cb.z, cb.w + q2)));
        int ka = (__float_as_int(da) & MASK13) | ja;
        int kb = (__float_as_int(db) & MASK13) | jb;
        ka = (ja == query) ? IMAX : ka;
        kb = (jb == query) ? IMAX : kb;
        ins2(l, ka, kb);
    }
#pragma unroll
    for (int k = 0; k < KNN; ++k) mv[(wv * KNN + k) * QPB + lane] = l[k];
    __syncthreads();
    if (threadIdx.x < QPB) {
        int m[KNN];
#pragma unroll
        for (int k = 0; k < KNN; ++k) m[k] = IMAX;
#pragma unroll
        for (int e = 0; e < WPB; ++e) {
            int p[KNN];
#pragma unroll
            for (int k = 0; k < KNN; ++k) p[k] = mv[(e * KNN + k) * QPB + lane];
            merge_sorted(m, p);
        }
        const float* P2b = p2 + (size_t)batch * NPTS * 3;
        float s1x = 0, s1y = 0, s1z = 0, s2x = 0, s2y = 0, s2z = 0;
#pragma unroll
        for (int k = 0; k < KNN; ++k) {
            const int j = m[k] & (NPTS - 1);
            const float4 c = Wb[j];
            s1x += c.x; s1y += c.y; s1z += c.z;
            s2x += P2b[3 * j + 0]; s2y += P2b[3 * j + 1]; s2z += P2b[3 * j + 2];
        }
        const int q = qbase + threadIdx.x;
        const float p2x = P2b[3 * q + 0], p2y = P2b[3 * q + 1], p2z = P2b[3 * q + 2];
        const float dx = (s1x * 0.1f - qp.x) - (s2x * 0.1f - p2x);
        const float dy = (s1y * 0.1f - qp.y) - (s2y * 0.1f - p2y);
        const float dz = (s1z * 0.1f - qp.z) - (s2z * 0.1f - p2z);
        float v = fabsf(dx) + fabsf(dy) + fabsf(dz);
#pragma unroll
        for (int off = 32; off >= 1; off >>= 1) v += __shfl_down(v, off);
        if (threadIdx.x == 0)
            atomicAdd(out, v * (1.0f / (float)(NB * NPTS * 3)));
    }
}

// ---------------- launcher ----------------
extern "C" void kernel_launch(void* const* d_in, const int* in_sizes, int n_in,
                              void* d_out, int out_size, void* d_ws, size_t ws_size,
                              hipStream_t stream) {
    const float* p1 = (const float*)d_in[0];
    const float* p2 = (const float*)d_in[1];
    float* out = (float*)d_out;

    size_t off = 0;
    float4* w       = (float4*)d_ws;               off += (size_t)NB * NPTS * 16;
    int*    hist    = (int*)((char*)d_ws + off);   off += (size_t)NB * NC * 4;
    int*    starts  = (int*)((char*)d_ws + off);   off += (size_t)NB * (NC + 1) * 4 + 8;
    int*    cellof  = (int*)((char*)d_ws + off);   off += (size_t)NB * NPTS * 4;
    float4* wsorted = (float4*)((char*)d_ws + off); off += (size_t)NB * NPTS * 16;
    float4* p2s     = (float4*)((char*)d_ws + off); off += (size_t)NB * NPTS * 16;
    int*    nfail   = (int*)((char*)d_ws + off);   off += 16;
    int*    worklist= (int*)((char*)d_ws + off);   off += (size_t)NB * NPTS * 4;

    if (ws_size < off) {  // fallback: round-2 brute force
        hipMemsetAsync(out, 0, sizeof(float), stream);
        prep_pack<<<(NB * NPTS + 255) / 256, 256, 0, stream>>>(p1, w);
        knn_lap<<<NB * (NPTS / QPB), BLOCK, 0, stream>>>(w, p2, out);
        return;
    }

    hipMemsetAsync(hist, 0, (size_t)NB * NC * 4, stream);
    pack_bin<<<(NB * NPTS + 255) / 256, 256, 0, stream>>>(p1, w, hist, cellof,
                                                          out, nfail);
    scan_scatter<<<NB, 1024, 0, stream>>>(hist, starts, cellof, w, p2,
                                          wsorted, p2s);
    phase1<<<NB * (NPTS / QPB), BLOCK, 0, stream>>>(wsorted, p2s, starts, out,
                                                    nfail, worklist);
    phase2<<<P2GRID, P2BLK, 0, stream>>>(wsorted, p2s, nfail, worklist, out);
}

// Round 9
// 124.378 us; speedup vs baseline: 1.2948x; 1.2948x over previous
//
#include <hip/hip_runtime.h>
#include <math.h>

// PointLaplacianLoss — grid-pruned exact KNN, round 9.
//
// Round-8 lesson: fusing scatter into the 2-block scan kernel put 16K
// scattered atomic+store round-trips on 0.3% occupancy -> 52 us. Un-fuse:
// scan_cells <<<NB,1024>>> (scan only), scatter_all <<<64,256>>> (as round 7).
// Keep round-8 phase1 (wave-uniform rectangle scan over the block's merged
// 3^3 neighborhoods when queries span <=2 cell-rows; per-lane gather
// fallback otherwise) and phase2 (wave-per-failed-query brute force).

constexpr int NPTS  = 8192;
constexpr int NB    = 2;
constexpr int KNN   = 10;
constexpr int QPB   = 64;
constexpr int WPB   = 8;
constexpr int BLOCK = QPB * WPB;        // 512
constexpr int MASK13 = 0xFFFFE000;

constexpr int   G    = 32;
constexpr int   NC   = G * G * G;
constexpr float BMIN = -5.5f;
constexpr float BW   = 11.0f;
constexpr float H    = BW / G;          // 0.34375
constexpr float INVH = (float)G / BW;

__device__ __forceinline__ int iabs(int v) { return v < 0 ? -v : v; }

// ---------------- selection helpers ----------------
__device__ __forceinline__ void ins1(int l[KNN], int x) {
#pragma unroll
    for (int k = KNN - 1; k > 0; --k) l[k] = min(l[k], max(l[k - 1], x));
    l[0] = min(l[0], x);
}
__device__ __forceinline__ void ins2(int l[KNN], int a, int b) {
    const int b0 = min(a, b), b1 = max(a, b);
#pragma unroll
    for (int k = KNN - 1; k >= 2; --k)
        l[k] = min(l[k], min(max(l[k - 1], b0), max(l[k - 2], b1)));
    l[1] = min(l[1], min(max(l[0], b0), b1));
    l[0] = min(l[0], b0);
}
template<int S>
__device__ __forceinline__ void ins2s(int l[KNN], int a, int b) {
    const int b0 = min(a, b), b1 = max(a, b);
#pragma unroll
    for (int k = KNN - 1; k >= S + 2; --k)
        l[k] = min(l[k], min(max(l[k - 1], b0), max(l[k - 2], b1)));
    l[S + 1] = min(l[S + 1], min(max(l[S], b0), b1));
    l[S] = min(l[S], b0);
}
__device__ __forceinline__ void merge_sorted(int l[KNN], const int p[KNN]) {
    ins2s<0>(l, p[0], p[1]);
    ins2s<2>(l, p[2], p[3]);
    ins2s<4>(l, p[4], p[5]);
    ins2s<6>(l, p[6], p[7]);
    ins2s<8>(l, p[8], p[9]);
}

// ---------------- build kernels ----------------
__global__ void pack_bin(const float* __restrict__ p1, float4* __restrict__ w,
                         int* __restrict__ hist, int* __restrict__ cellof,
                         float* __restrict__ out, int* __restrict__ nfail) {
    const int i = blockIdx.x * blockDim.x + threadIdx.x;
    if (i >= NB * NPTS) return;
    if (i == 0) { out[0] = 0.0f; nfail[0] = 0; }
    const float x = p1[3 * i], y = p1[3 * i + 1], z = p1[3 * i + 2];
    w[i] = make_float4(x, y, z, fmaf(x, x, fmaf(y, y, z * z)));
    const int cx = min(max((int)floorf((x - BMIN) * INVH), 0), G - 1);
    const int cy = min(max((int)floorf((y - BMIN) * INVH), 0), G - 1);
    const int cz = min(max((int)floorf((z - BMIN) * INVH), 0), G - 1);
    const int c = (cz << 10) | (cy << 5) | cx;
    cellof[i] = c;
    atomicAdd(&hist[(i >> 13) * NC + c], 1);
}

__global__ __launch_bounds__(1024)
void scan_cells(const int* __restrict__ hist, int* __restrict__ starts) {
    __shared__ int wsum[16];
    const int b = blockIdx.x, t = threadIdx.x;
    const int* hb = hist + b * NC;
    int* sb = starts + b * (NC + 1);
    const int c0 = t * 32;
    int loc[32]; int sum = 0;
#pragma unroll
    for (int j = 0; j < 32; ++j) { loc[j] = hb[c0 + j]; sum += loc[j]; }
    const int lane = t & 63, wvi = t >> 6;
    int incl = sum;
#pragma unroll
    for (int off = 1; off < 64; off <<= 1) {
        const int v = __shfl_up(incl, off);
        if (lane >= off) incl += v;
    }
    if (lane == 63) wsum[wvi] = incl;
    __syncthreads();
    if (t < 16) {
        const int v = wsum[t];
        int iv = v;
#pragma unroll
        for (int off = 1; off < 16; off <<= 1) {
            const int u = __shfl_up(iv, off);
            if (t >= off) iv += u;
        }
        wsum[t] = iv - v;
    }
    __syncthreads();
    int run = wsum[wvi] + incl - sum;
#pragma unroll
    for (int j = 0; j < 32; ++j) { sb[c0 + j] = run; run += loc[j]; }
    if (t == 1023) sb[NC] = run;
}

__global__ void scatter_all(const int* __restrict__ cellof,
                            const int* __restrict__ starts,
                            int* __restrict__ hist,
                            const float4* __restrict__ w,
                            const float* __restrict__ p2,
                            float4* __restrict__ wsorted,
                            float4* __restrict__ p2s) {
    const int i = blockIdx.x * blockDim.x + threadIdx.x;
    if (i >= NB * NPTS) return;
    const int b = i >> 13;
    const int c = cellof[i];
    const int old = atomicSub(&hist[b * NC + c], 1);
    const int pos = b * NPTS + starts[b * (NC + 1) + c] + old - 1;
    wsorted[pos] = w[i];
    p2s[pos] = make_float4(p2[3 * i], p2[3 * i + 1], p2[3 * i + 2], 0.0f);
}

// ---------------- phase 1 ----------------
__global__ __launch_bounds__(BLOCK)
void phase1(const float4* __restrict__ wsorted, const float4* __restrict__ p2s,
            const int* __restrict__ starts, float* __restrict__ out,
            int* __restrict__ nfail, int* __restrict__ worklist)
{
    __shared__ int mv[WPB * KNN * QPB];      // 20 KB

    const int batch = blockIdx.x >> 7;
    const int lane  = threadIdx.x & 63;
    const int wv    = __builtin_amdgcn_readfirstlane(threadIdx.x >> 6);
    const int qpos  = ((blockIdx.x & 127) << 6) + lane;

    const float4* W  = wsorted + batch * NPTS;
    const float4* P2 = p2s + batch * NPTS;
    const int*    st = starts + batch * (NC + 1);

    const float4 qp = W[qpos];
    const int cx = min(max((int)floorf((qp.x - BMIN) * INVH), 0), G - 1);
    const int cy = min(max((int)floorf((qp.y - BMIN) * INVH), 0), G - 1);
    const int cz = min(max((int)floorf((qp.z - BMIN) * INVH), 0), G - 1);
    const float lox = BMIN + cx * H, loy = BMIN + cy * H, loz = BMIN + cz * H;
    const float df = fminf(fminf(fminf(qp.x - lox, lox + H - qp.x),
                                 fminf(qp.y - loy, loy + H - qp.y)),
                           fminf(qp.z - loz, loz + H - qp.z));
    const float m2x = -2.0f * qp.x, m2y = -2.0f * qp.y, m2z = -2.0f * qp.z;
    const float q2 = qp.w;
    const int IMAX = 0x7FFFFFFF;

    int l[KNN];
#pragma unroll
    for (int k = 0; k < KNN; ++k) l[k] = IMAX;
    int sCov = 1;

    // ---- block-uniform group analysis (every wave sees identical lanes) ----
    const int rowid = (cz << 5) | cy;
    int rmin = rowid, rmax = rowid;
#pragma unroll
    for (int off = 32; off >= 1; off >>= 1) {
        rmin = min(rmin, __shfl_xor(rmin, off));
        rmax = max(rmax, __shfl_xor(rmax, off));
    }
    bool two = false;
    bool uni = (rmax == rmin);
    if (!uni) {
        const unsigned long long m0 = __ballot(rowid == rmin);
        const unsigned long long m1 = __ballot(rowid == rmax);
        if ((m0 | m1) == 0xFFFFFFFFFFFFFFFFull) { uni = true; two = true; }
    }
    if (uni) {
        int x0mn = (rowid == rmin) ? cx : 999;
        int x0mx = (rowid == rmin) ? cx : -999;
        int x1mn = (rowid == rmax) ? cx : 999;
        int x1mx = (rowid == rmax) ? cx : -999;
#pragma unroll
        for (int off = 32; off >= 1; off >>= 1) {
            x0mn = min(x0mn, __shfl_xor(x0mn, off));
            x0mx = max(x0mx, __shfl_xor(x0mx, off));
            x1mn = min(x1mn, __shfl_xor(x1mn, off));
            x1mx = max(x1mx, __shfl_xor(x1mx, off));
        }
        if (x0mx - x0mn > 6 || (two && (x1mx - x1mn > 6))) uni = false;
        if (uni) {
            const int gy0 = __builtin_amdgcn_readfirstlane(rmin & 31);
            const int gz0 = __builtin_amdgcn_readfirstlane(rmin >> 5);
            const int gy1 = __builtin_amdgcn_readfirstlane(rmax & 31);
            const int gz1 = __builtin_amdgcn_readfirstlane(rmax >> 5);
            const int w0lo = __builtin_amdgcn_readfirstlane(max(x0mn - 1, 0));
            const int w0hi = __builtin_amdgcn_readfirstlane(min(x0mx + 1, G - 1));
            const int w1lo = __builtin_amdgcn_readfirstlane(max(x1mn - 1, 0));
            const int w1hi = __builtin_amdgcn_readfirstlane(min(x1mx + 1, G - 1));
            const int ng = two ? 2 : 1;
            for (int g = 0; g < ng; ++g) {
                const int gy = g ? gy1 : gy0, gz = g ? gz1 : gz0;
                const int oy = g ? gy0 : gy1, oz = g ? gz0 : gz1;
#pragma unroll
                for (int dz = -1; dz <= 1; ++dz)
#pragma unroll
                for (int dy = -1; dy <= 1; ++dy) {
                    const int ay = gy + dy, az = gz + dz;
                    if ((unsigned)ay >= G || (unsigned)az >= G) continue;
                    const bool cOther = two && (iabs(ay - oy) <= 1) &&
                                               (iabs(az - oz) <= 1);
                    if (g == 1 && cOther) continue;     // scanned in g0 (merged)
                    int xlo = g ? w1lo : w0lo;
                    int xhi = g ? w1hi : w0hi;
                    if (g == 0 && cOther) { xlo = min(xlo, w1lo); xhi = max(xhi, w1hi); }
                    const int cbase = (az << 10) | (ay << 5);
                    const int j0 = __builtin_amdgcn_readfirstlane(st[cbase + xlo]);
                    const int j1 = __builtin_amdgcn_readfirstlane(st[cbase + xhi + 1]);
                    int j = j0 + wv;
                    for (; j + WPB < j1; j += 2 * WPB) {      // wave-uniform j
                        const float4 ca = W[j];
                        const float4 cb = W[j + WPB];
                        const float da = fmaf(m2x, ca.x, fmaf(m2y, ca.y,
                                         fmaf(m2z, ca.z, ca.w + q2)));
                        const float db = fmaf(m2x, cb.x, fmaf(m2y, cb.y,
                                         fmaf(m2z, cb.z, cb.w + q2)));
                        int ka = (__float_as_int(da) & MASK13) | j;
                        int kb = (__float_as_int(db) & MASK13) | (j + WPB);
                        ka = (j == qpos) ? IMAX : ka;
                        kb = (j + WPB == qpos) ? IMAX : kb;
                        ins2(l, ka, kb);
                    }
                    if (j < j1) {
                        const float4 ca = W[j];
                        const float da = fmaf(m2x, ca.x, fmaf(m2y, ca.y,
                                         fmaf(m2z, ca.z, ca.w + q2)));
                        int ka = (__float_as_int(da) & MASK13) | j;
                        ka = (j == qpos) ? IMAX : ka;
                        ins1(l, ka);
                    }
                }
            }
        }
    }
    if (!uni) {
        // ---- per-lane adaptive gather fallback (round 7) ----
        sCov = (q2 > 4.8f) ? 2 : 1;
        const int runs = (sCov == 1) ? 9 : 25;
        for (int r = 0; r < 25; ++r) {
            if (!__any(r < runs)) break;
            if (r < runs) {
                int dz3 = (r * 86) >> 8;
                const int dy3 = r - 3 * dz3 - 1;  dz3 -= 1;
                int dz5 = (r * 52429) >> 18;
                const int dy5 = r - 5 * dz5 - 2;  dz5 -= 2;
                const int dy = (sCov == 1) ? dy3 : dy5;
                const int dz = (sCov == 1) ? dz3 : dz5;
                const int ay = cy + dy, az = cz + dz;
                int j0 = 0, j1 = 0;
                if ((unsigned)ay < G && (unsigned)az < G) {
                    const int cbase = (az << 10) | (ay << 5);
                    j0 = st[cbase + max(cx - sCov, 0)];
                    j1 = st[cbase + min(cx + sCov, G - 1) + 1];
                }
                int j = j0 + wv;
                if (j < j1) {
                    float4 c4 = W[j];
                    while (true) {
                        const int jn = j + WPB;
                        const bool more = jn < j1;
                        float4 nx;
                        if (more) nx = W[jn];
                        const float d2 = fmaf(m2x, c4.x, fmaf(m2y, c4.y,
                                         fmaf(m2z, c4.z, c4.w + q2)));
                        int key = (__float_as_int(d2) & MASK13) | j;
                        key = (j == qpos) ? IMAX : key;
                        ins1(l, key);
                        if (!more) break;
                        c4 = nx; j = jn;
                    }
                }
            }
        }
    }

#pragma unroll
    for (int k = 0; k < KNN; ++k) mv[(wv * KNN + k) * QPB + lane] = l[k];
    __syncthreads();

    if (threadIdx.x < QPB) {
        int M[KNN];
#pragma unroll
        for (int k = 0; k < KNN; ++k) M[k] = IMAX;
#pragma unroll
        for (int e = 0; e < WPB; ++e) {
            int p[KNN];
#pragma unroll
            for (int k = 0; k < KNN; ++k) p[k] = mv[(e * KNN + k) * QPB + lane];
            merge_sorted(M, p);
        }

        const float tau = __int_as_float(M[KNN - 1] & MASK13);
        const float R = (float)sCov * H + df;
        const bool covered = (tau <= R * R * 0.996f);
        float v = 0.0f;
        if (covered) {
            float s1x = 0, s1y = 0, s1z = 0, s2x = 0, s2y = 0, s2z = 0;
#pragma unroll
            for (int k = 0; k < KNN; ++k) {
                const int j = M[k] & (NPTS - 1);
                const float4 c4 = W[j];
                const float4 n2 = P2[j];
                s1x += c4.x; s1y += c4.y; s1z += c4.z;
                s2x += n2.x; s2y += n2.y; s2z += n2.z;
            }
            const float4 p2v = P2[qpos];
            const float dx = (s1x * 0.1f - qp.x) - (s2x * 0.1f - p2v.x);
            const float dy2 = (s1y * 0.1f - qp.y) - (s2y * 0.1f - p2v.y);
            const float dz2 = (s1z * 0.1f - qp.z) - (s2z * 0.1f - p2v.z);
            v = fabsf(dx) + fabsf(dy2) + fabsf(dz2);
        } else {
            const int wi = atomicAdd(nfail, 1);
            worklist[wi] = (batch << 16) | qpos;
        }
#pragma unroll
        for (int off = 32; off >= 1; off >>= 1) v += __shfl_down(v, off);
        if (threadIdx.x == 0)
            atomicAdd(out, v * (1.0f / (float)(NB * NPTS * 3)));
    }
}

// ---------------- phase 2: wave-per-query exact brute force ----------------
constexpr int P2BLK = 256;
constexpr int P2GRID = 512;

__global__ __launch_bounds__(P2BLK)
void phase2(const float4* __restrict__ wsorted, const float4* __restrict__ p2s,
            const int* __restrict__ nfail, const int* __restrict__ worklist,
            float* __restrict__ out)
{
    const int lane = threadIdx.x & 63;
    const int wv   = threadIdx.x >> 6;
    const int wid  = blockIdx.x * (P2BLK / 64) + wv;
    const int NW   = P2GRID * (P2BLK / 64);
    const int nf   = *nfail;
    const int IMAX = 0x7FFFFFFF;
    float acc = 0.0f;

    for (int i = wid; i < nf; i += NW) {
        const int e = worklist[i];
        const int batch = e >> 16, qpos = e & 0xFFFF;
        const float4* W  = wsorted + batch * NPTS;
        const float4* P2 = p2s + batch * NPTS;
        const float4 qp = W[qpos];
        const float m2x = -2.0f * qp.x, m2y = -2.0f * qp.y, m2z = -2.0f * qp.z;
        const float q2 = qp.w;

        int l[KNN];
#pragma unroll
        for (int k = 0; k < KNN; ++k) l[k] = IMAX;

#pragma unroll 2
        for (int it = 0; it < NPTS / 128; ++it) {
            const int ja = it * 128 + lane, jb = ja + 64;
            const float4 ca = W[ja];
            const float4 cb = W[jb];
            const float da = fmaf(m2x, ca.x, fmaf(m2y, ca.y, fmaf(m2z, ca.z, ca.w + q2)));
            const float db = fmaf(m2x, cb.x, fmaf(m2y, cb.y, fmaf(m2z, cb.z, cb.w + q2)));
            int ka = (__float_as_int(da) & MASK13) | ja;
            int kb = (__float_as_int(db) & MASK13) | jb;
            ka = (ja == qpos) ? IMAX : ka;
            kb = (jb == qpos) ? IMAX : kb;
            ins2(l, ka, kb);
        }
        for (int off = 1; off < 64; off <<= 1) {
            int p[KNN];
#pragma unroll
            for (int k = 0; k < KNN; ++k) p[k] = __shfl_xor(l[k], off);
            merge_sorted(l, p);
        }
        float s1x = 0, s1y = 0, s1z = 0, s2x = 0, s2y = 0, s2z = 0;
#pragma unroll
        for (int k = 0; k < KNN; ++k) {
            const int j = l[k] & (NPTS - 1);
            const float4 c4 = W[j];
            const float4 n2 = P2[j];
            s1x += c4.x; s1y += c4.y; s1z += c4.z;
            s2x += n2.x; s2y += n2.y; s2z += n2.z;
        }
        const float4 p2v = P2[qpos];
        const float dx = (s1x * 0.1f - qp.x) - (s2x * 0.1f - p2v.x);
        const float dy = (s1y * 0.1f - qp.y) - (s2y * 0.1f - p2v.y);
        const float dz = (s1z * 0.1f - qp.z) - (s2z * 0.1f - p2v.z);
        if (lane == 0) acc += fabsf(dx) + fabsf(dy) + fabsf(dz);
    }

    if (lane == 0 && acc != 0.0f)
        atomicAdd(out, acc * (1.0f / (float)(NB * NPTS * 3)));
}

// ---------------- round-2 fallback (O(N^2), verified) ----------------
constexpr int CHUNK = NPTS / WPB;

__global__ void prep_pack(const float* __restrict__ p, float4* __restrict__ w) {
    const int i = blockIdx.x * blockDim.x + threadIdx.x;
    if (i < NB * NPTS) {
        const float x = p[3 * i], y = p[3 * i + 1], z = p[3 * i + 2];
        w[i] = make_float4(x, y, z, fmaf(x, x, fmaf(y, y, z * z)));
    }
}

__global__ __launch_bounds__(BLOCK, 2)
void knn_lap(const float4* __restrict__ w1, const float* __restrict__ p2,
             float* __restrict__ out)
{
    __shared__ int mv[WPB * KNN * QPB];
    const int batch = blockIdx.x >> 7;
    const int qbase = (blockIdx.x & 127) << 6;
    const int lane  = threadIdx.x & 63;
    const int wv    = __builtin_amdgcn_readfirstlane(threadIdx.x >> 6);
    const int query = qbase + lane;
    const float4* Wb = w1 + batch * NPTS;
    const float4 qp = Wb[query];
    const float m2x = -2.0f * qp.x, m2y = -2.0f * qp.y, m2z = -2.0f * qp.z;
    const float q2 = qp.w;
    const int IMAX = 0x7FFFFFFF;
    int l[KNN];
#pragma unroll
    for (int k = 0; k < KNN; ++k) l[k] = IMAX;
    const int c0 = wv * CHUNK;
    const float4* cand = Wb + c0;
#pragma unroll 4
    for (int i = 0; i < CHUNK; i += 2) {
        const float4 ca = cand[i];
        const float4 cb = cand[i + 1];
        const int ja = c0 + i, jb = ja + 1;
        const float da = fmaf(m2x, ca.x, fmaf(m2y, ca.y, fmaf(m2z, ca.z, ca.w + q2)));
        const float db = fmaf(m2x, cb.x, fmaf(m2y, cb.y, fmaf(m2z, cb.z, cb.w + q2)));
        int ka = (__float_as_int(da) & MASK13) | ja;
        int kb = (__float_as_int(db) & MASK13) | jb;
        ka = (ja == query) ? IMAX : ka;
        kb = (jb == query) ? IMAX : kb;
        ins2(l, ka, kb);
    }
#pragma unroll
    for (int k = 0; k < KNN; ++k) mv[(wv * KNN + k) * QPB + lane] = l[k];
    __syncthreads();
    if (threadIdx.x < QPB) {
        int m[KNN];
#pragma unroll
        for (int k = 0; k < KNN; ++k) m[k] = IMAX;
#pragma unroll
        for (int e = 0; e < WPB; ++e) {
            int p[KNN];
#pragma unroll
            for (int k = 0; k < KNN; ++k) p[k] = mv[(e * KNN + k) * QPB + lane];
            merge_sorted(m, p);
        }
        const float* P2b = p2 + (size_t)batch * NPTS * 3;
        float s1x = 0, s1y = 0, s1z = 0, s2x = 0, s2y = 0, s2z = 0;
#pragma unroll
        for (int k = 0; k < KNN; ++k) {
            const int j = m[k] & (NPTS - 1);
            const float4 c = Wb[j];
            s1x += c.x; s1y += c.y; s1z += c.z;
            s2x += P2b[3 * j + 0]; s2y += P2b[3 * j + 1]; s2z += P2b[3 * j + 2];
        }
        const int q = qbase + threadIdx.x;
        const float p2x = P2b[3 * q + 0], p2y = P2b[3 * q + 1], p2z = P2b[3 * q + 2];
        const float dx = (s1x * 0.1f - qp.x) - (s2x * 0.1f - p2x);
        const float dy = (s1y * 0.1f - qp.y) - (s2y * 0.1f - p2y);
        const float dz = (s1z * 0.1f - qp.z) - (s2z * 0.1f - p2z);
        float v = fabsf(dx) + fabsf(dy) + fabsf(dz);
#pragma unroll
        for (int off = 32; off >= 1; off >>= 1) v += __shfl_down(v, off);
        if (threadIdx.x == 0)
            atomicAdd(out, v * (1.0f / (float)(NB * NPTS * 3)));
    }
}

// ---------------- launcher ----------------
extern "C" void kernel_launch(void* const* d_in, const int* in_sizes, int n_in,
                              void* d_out, int out_size, void* d_ws, size_t ws_size,
                              hipStream_t stream) {
    const float* p1 = (const float*)d_in[0];
    const float* p2 = (const float*)d_in[1];
    float* out = (float*)d_out;

    size_t off = 0;
    float4* w       = (float4*)d_ws;               off += (size_t)NB * NPTS * 16;
    int*    hist    = (int*)((char*)d_ws + off);   off += (size_t)NB * NC * 4;
    int*    starts  = (int*)((char*)d_ws + off);   off += (size_t)NB * (NC + 1) * 4 + 8;
    int*    cellof  = (int*)((char*)d_ws + off);   off += (size_t)NB * NPTS * 4;
    float4* wsorted = (float4*)((char*)d_ws + off); off += (size_t)NB * NPTS * 16;
    float4* p2s     = (float4*)((char*)d_ws + off); off += (size_t)NB * NPTS * 16;
    int*    nfail   = (int*)((char*)d_ws + off);   off += 16;
    int*    worklist= (int*)((char*)d_ws + off);   off += (size_t)NB * NPTS * 4;

    if (ws_size < off) {  // fallback: round-2 brute force
        hipMemsetAsync(out, 0, sizeof(float), stream);
        prep_pack<<<(NB * NPTS + 255) / 256, 256, 0, stream>>>(p1, w);
        knn_lap<<<NB * (NPTS / QPB), BLOCK, 0, stream>>>(w, p2, out);
        return;
    }

    hipMemsetAsync(hist, 0, (size_t)NB * NC * 4, stream);
    pack_bin<<<(NB * NPTS + 255) / 256, 256, 0, stream>>>(p1, w, hist, cellof,
                                                          out, nfail);
    scan_cells<<<NB, 1024, 0, stream>>>(hist, starts);
    scatter_all<<<(NB * NPTS + 255) / 256, 256, 0, stream>>>(cellof, starts, hist,
                                                             w, p2, wsorted, p2s);
    phase1<<<NB * (NPTS / QPB), BLOCK, 0, stream>>>(wsorted, p2s, starts, out,
                                                    nfail, worklist);
    phase2<<<P2GRID, P2BLK, 0, stream>>>(wsorted, p2s, nfail, worklist, out);
}

// Round 10
// 120.855 us; speedup vs baseline: 1.3326x; 1.0292x over previous
//
#include <hip/hip_runtime.h>
#include <math.h>

// PointLaplacianLoss — grid-pruned exact KNN, round 10.
//
// Round-9 lesson: the rect path was neutral; phase1's real cost is sparse
// waves serializing 25 (bounds-load -> wait -> short gather) round-trips at
// 2 waves/SIMD. This round:
//   * scan_batched<S>: fully-unrolled, loads ALL run bounds (18 or 50
//     independent loads) into registers BEFORE the first gather — the
//     25-deep dependent chain collapses to ~1 round-trip.
//   * WPB 8->16 (BLOCK=1024, 4 waves/SIMD): halves each wave's chain and
//     doubles TLP. LDS merge = 16 lists (40 KB).
//   * rect path dropped; per-lane adaptive s (3^3 / 5^3) kept; phase2 and
//     the build pipeline unchanged from round 9.

constexpr int NPTS  = 8192;
constexpr int NB    = 2;
constexpr int KNN   = 10;
constexpr int QPB   = 64;
constexpr int WPB   = 16;               // wave-slices per query (was 8)
constexpr int BLOCK = QPB * WPB;        // 1024
constexpr int MASK13 = 0xFFFFE000;

constexpr int   G    = 32;
constexpr int   NC   = G * G * G;
constexpr float BMIN = -5.5f;
constexpr float BW   = 11.0f;
constexpr float H    = BW / G;          // 0.34375
constexpr float INVH = (float)G / BW;

// ---------------- selection helpers ----------------
__device__ __forceinline__ void ins1(int l[KNN], int x) {
#pragma unroll
    for (int k = KNN - 1; k > 0; --k) l[k] = min(l[k], max(l[k - 1], x));
    l[0] = min(l[0], x);
}
__device__ __forceinline__ void ins2(int l[KNN], int a, int b) {
    const int b0 = min(a, b), b1 = max(a, b);
#pragma unroll
    for (int k = KNN - 1; k >= 2; --k)
        l[k] = min(l[k], min(max(l[k - 1], b0), max(l[k - 2], b1)));
    l[1] = min(l[1], min(max(l[0], b0), b1));
    l[0] = min(l[0], b0);
}
template<int S>
__device__ __forceinline__ void ins2s(int l[KNN], int a, int b) {
    const int b0 = min(a, b), b1 = max(a, b);
#pragma unroll
    for (int k = KNN - 1; k >= S + 2; --k)
        l[k] = min(l[k], min(max(l[k - 1], b0), max(l[k - 2], b1)));
    l[S + 1] = min(l[S + 1], min(max(l[S], b0), b1));
    l[S] = min(l[S], b0);
}
__device__ __forceinline__ void merge_sorted(int l[KNN], const int p[KNN]) {
    ins2s<0>(l, p[0], p[1]);
    ins2s<2>(l, p[2], p[3]);
    ins2s<4>(l, p[4], p[5]);
    ins2s<6>(l, p[6], p[7]);
    ins2s<8>(l, p[8], p[9]);
}

// ---------------- build kernels ----------------
__global__ void pack_bin(const float* __restrict__ p1, float4* __restrict__ w,
                         int* __restrict__ hist, int* __restrict__ cellof,
                         float* __restrict__ out, int* __restrict__ nfail) {
    const int i = blockIdx.x * blockDim.x + threadIdx.x;
    if (i >= NB * NPTS) return;
    if (i == 0) { out[0] = 0.0f; nfail[0] = 0; }
    const float x = p1[3 * i], y = p1[3 * i + 1], z = p1[3 * i + 2];
    w[i] = make_float4(x, y, z, fmaf(x, x, fmaf(y, y, z * z)));
    const int cx = min(max((int)floorf((x - BMIN) * INVH), 0), G - 1);
    const int cy = min(max((int)floorf((y - BMIN) * INVH), 0), G - 1);
    const int cz = min(max((int)floorf((z - BMIN) * INVH), 0), G - 1);
    const int c = (cz << 10) | (cy << 5) | cx;
    cellof[i] = c;
    atomicAdd(&hist[(i >> 13) * NC + c], 1);
}

__global__ __launch_bounds__(1024)
void scan_cells(const int* __restrict__ hist, int* __restrict__ starts) {
    __shared__ int wsum[16];
    const int b = blockIdx.x, t = threadIdx.x;
    const int* hb = hist + b * NC;
    int* sb = starts + b * (NC + 1);
    const int c0 = t * 32;
    int loc[32]; int sum = 0;
#pragma unroll
    for (int j = 0; j < 32; ++j) { loc[j] = hb[c0 + j]; sum += loc[j]; }
    const int lane = t & 63, wvi = t >> 6;
    int incl = sum;
#pragma unroll
    for (int off = 1; off < 64; off <<= 1) {
        const int v = __shfl_up(incl, off);
        if (lane >= off) incl += v;
    }
    if (lane == 63) wsum[wvi] = incl;
    __syncthreads();
    if (t < 16) {
        const int v = wsum[t];
        int iv = v;
#pragma unroll
        for (int off = 1; off < 16; off <<= 1) {
            const int u = __shfl_up(iv, off);
            if (t >= off) iv += u;
        }
        wsum[t] = iv - v;
    }
    __syncthreads();
    int run = wsum[wvi] + incl - sum;
#pragma unroll
    for (int j = 0; j < 32; ++j) { sb[c0 + j] = run; run += loc[j]; }
    if (t == 1023) sb[NC] = run;
}

__global__ void scatter_all(const int* __restrict__ cellof,
                            const int* __restrict__ starts,
                            int* __restrict__ hist,
                            const float4* __restrict__ w,
                            const float* __restrict__ p2,
                            float4* __restrict__ wsorted,
                            float4* __restrict__ p2s) {
    const int i = blockIdx.x * blockDim.x + threadIdx.x;
    if (i >= NB * NPTS) return;
    const int b = i >> 13;
    const int c = cellof[i];
    const int old = atomicSub(&hist[b * NC + c], 1);
    const int pos = b * NPTS + starts[b * (NC + 1) + c] + old - 1;
    wsorted[pos] = w[i];
    p2s[pos] = make_float4(p2[3 * i], p2[3 * i + 1], p2[3 * i + 2], 0.0f);
}

// ---------------- phase 1: batched-bounds adaptive scan ----------------
// All run bounds loaded up-front as independent loads (one latency round-trip
// instead of (2S+1)^2 serialized ones), then the gather runs.
template<int S>
__device__ __forceinline__ void scan_batched(const float4* __restrict__ W,
                                             const int* __restrict__ st,
                                             int cx, int cy, int cz,
                                             float m2x, float m2y, float m2z,
                                             float q2, int qpos, int wv,
                                             int l[KNN])
{
    constexpr int Wd = 2 * S + 1;
    constexpr int R  = Wd * Wd;
    const int IMAX = 0x7FFFFFFF;
    int J0[R], J1[R];
#pragma unroll
    for (int r = 0; r < R; ++r) {
        const int dy = r % Wd - S, dz = r / Wd - S;   // compile-time
        const int ay = cy + dy, az = cz + dz;
        const bool ok = ((unsigned)ay < G) && ((unsigned)az < G);
        const int cbase = (az << 10) | (ay << 5);
        const int lo = cbase + max(cx - S, 0);
        const int hi = cbase + min(cx + S, G - 1) + 1;
        J0[r] = ok ? st[lo] : 0;                      // predicated, independent
        J1[r] = ok ? st[hi] : 0;
    }
#pragma unroll
    for (int r = 0; r < R; ++r) {
        const int j1 = J1[r];
        int j = J0[r] + wv;
        if (j < j1) {
            float4 c4 = W[j];                         // prime
            while (true) {
                const int jn = j + WPB;
                const bool more = jn < j1;
                float4 nx;
                if (more) nx = W[jn];                 // prefetch next
                const float d2 = fmaf(m2x, c4.x,
                                 fmaf(m2y, c4.y,
                                 fmaf(m2z, c4.z, c4.w + q2)));
                int key = (__float_as_int(d2) & MASK13) | j;
                key = (j == qpos) ? IMAX : key;
                ins1(l, key);
                if (!more) break;
                c4 = nx; j = jn;
            }
        }
    }
}

__global__ __launch_bounds__(BLOCK)
void phase1(const float4* __restrict__ wsorted, const float4* __restrict__ p2s,
            const int* __restrict__ starts, float* __restrict__ out,
            int* __restrict__ nfail, int* __restrict__ worklist)
{
    __shared__ int mv[WPB * KNN * QPB];      // 40 KB

    const int batch = blockIdx.x >> 7;
    const int lane  = threadIdx.x & 63;
    const int wv    = __builtin_amdgcn_readfirstlane(threadIdx.x >> 6);
    const int qpos  = ((blockIdx.x & 127) << 6) + lane;

    const float4* W  = wsorted + batch * NPTS;
    const float4* P2 = p2s + batch * NPTS;
    const int*    st = starts + batch * (NC + 1);

    const float4 qp = W[qpos];
    const int cx = min(max((int)floorf((qp.x - BMIN) * INVH), 0), G - 1);
    const int cy = min(max((int)floorf((qp.y - BMIN) * INVH), 0), G - 1);
    const int cz = min(max((int)floorf((qp.z - BMIN) * INVH), 0), G - 1);
    const float lox = BMIN + cx * H, loy = BMIN + cy * H, loz = BMIN + cz * H;
    const float df = fminf(fminf(fminf(qp.x - lox, lox + H - qp.x),
                                 fminf(qp.y - loy, loy + H - qp.y)),
                           fminf(qp.z - loz, loz + H - qp.z));
    const float m2x = -2.0f * qp.x, m2y = -2.0f * qp.y, m2z = -2.0f * qp.z;
    const float q2 = qp.w;
    const int IMAX = 0x7FFFFFFF;

    // per-lane reach (exec-masked): only truly-sparse lanes pay 5^3
    const int sCov = (q2 > 4.8f) ? 2 : 1;

    int l[KNN];
#pragma unroll
    for (int k = 0; k < KNN; ++k) l[k] = IMAX;

    if (sCov == 1)
        scan_batched<1>(W, st, cx, cy, cz, m2x, m2y, m2z, q2, qpos, wv, l);
    else
        scan_batched<2>(W, st, cx, cy, cz, m2x, m2y, m2z, q2, qpos, wv, l);

#pragma unroll
    for (int k = 0; k < KNN; ++k) mv[(wv * KNN + k) * QPB + lane] = l[k];
    __syncthreads();

    if (threadIdx.x < QPB) {
        int M[KNN];
#pragma unroll
        for (int k = 0; k < KNN; ++k) M[k] = IMAX;
#pragma unroll
        for (int e = 0; e < WPB; ++e) {
            int p[KNN];
#pragma unroll
            for (int k = 0; k < KNN; ++k) p[k] = mv[(e * KNN + k) * QPB + lane];
            merge_sorted(M, p);
        }

        const float tau = __int_as_float(M[KNN - 1] & MASK13);
        const float R = (float)sCov * H + df;         // per-lane coverage
        const bool covered = (tau <= R * R * 0.996f); // truncation margin
        float v = 0.0f;
        if (covered) {
            float s1x = 0, s1y = 0, s1z = 0, s2x = 0, s2y = 0, s2z = 0;
#pragma unroll
            for (int k = 0; k < KNN; ++k) {
                const int j = M[k] & (NPTS - 1);
                const float4 c4 = W[j];
                const float4 n2 = P2[j];
                s1x += c4.x; s1y += c4.y; s1z += c4.z;
                s2x += n2.x; s2y += n2.y; s2z += n2.z;
            }
            const float4 p2v = P2[qpos];
            const float dx = (s1x * 0.1f - qp.x) - (s2x * 0.1f - p2v.x);
            const float dy2 = (s1y * 0.1f - qp.y) - (s2y * 0.1f - p2v.y);
            const float dz2 = (s1z * 0.1f - qp.z) - (s2z * 0.1f - p2v.z);
            v = fabsf(dx) + fabsf(dy2) + fabsf(dz2);
        } else {
            const int wi = atomicAdd(nfail, 1);
            worklist[wi] = (batch << 16) | qpos;
        }
#pragma unroll
        for (int off = 32; off >= 1; off >>= 1) v += __shfl_down(v, off);
        if (threadIdx.x == 0)
            atomicAdd(out, v * (1.0f / (float)(NB * NPTS * 3)));
    }
}

// ---------------- phase 2: wave-per-query exact brute force ----------------
constexpr int P2BLK = 256;
constexpr int P2GRID = 512;

__global__ __launch_bounds__(P2BLK)
void phase2(const float4* __restrict__ wsorted, const float4* __restrict__ p2s,
            const int* __restrict__ nfail, const int* __restrict__ worklist,
            float* __restrict__ out)
{
    const int lane = threadIdx.x & 63;
    const int wv   = threadIdx.x >> 6;
    const int wid  = blockIdx.x * (P2BLK / 64) + wv;
    const int NW   = P2GRID * (P2BLK / 64);
    const int nf   = *nfail;
    const int IMAX = 0x7FFFFFFF;
    float acc = 0.0f;

    for (int i = wid; i < nf; i += NW) {
        const int e = worklist[i];
        const int batch = e >> 16, qpos = e & 0xFFFF;
        const float4* W  = wsorted + batch * NPTS;
        const float4* P2 = p2s + batch * NPTS;
        const float4 qp = W[qpos];
        const float m2x = -2.0f * qp.x, m2y = -2.0f * qp.y, m2z = -2.0f * qp.z;
        const float q2 = qp.w;

        int l[KNN];
#pragma unroll
        for (int k = 0; k < KNN; ++k) l[k] = IMAX;

#pragma unroll 2
        for (int it = 0; it < NPTS / 128; ++it) {
            const int ja = it * 128 + lane, jb = ja + 64;
            const float4 ca = W[ja];
            const float4 cb = W[jb];
            const float da = fmaf(m2x, ca.x, fmaf(m2y, ca.y, fmaf(m2z, ca.z, ca.w + q2)));
            const float db = fmaf(m2x, cb.x, fmaf(m2y, cb.y, fmaf(m2z, cb.z, cb.w + q2)));
            int ka = (__float_as_int(da) & MASK13) | ja;
            int kb = (__float_as_int(db) & MASK13) | jb;
            ka = (ja == qpos) ? IMAX : ka;
            kb = (jb == qpos) ? IMAX : kb;
            ins2(l, ka, kb);
        }
        for (int off = 1; off < 64; off <<= 1) {
            int p[KNN];
#pragma unroll
            for (int k = 0; k < KNN; ++k) p[k] = __shfl_xor(l[k], off);
            merge_sorted(l, p);
        }
        float s1x = 0, s1y = 0, s1z = 0, s2x = 0, s2y = 0, s2z = 0;
#pragma unroll
        for (int k = 0; k < KNN; ++k) {
            const int j = l[k] & (NPTS - 1);
            const float4 c4 = W[j];
            const float4 n2 = P2[j];
            s1x += c4.x; s1y += c4.y; s1z += c4.z;
            s2x += n2.x; s2y += n2.y; s2z += n2.z;
        }
        const float4 p2v = P2[qpos];
        const float dx = (s1x * 0.1f - qp.x) - (s2x * 0.1f - p2v.x);
        const float dy = (s1y * 0.1f - qp.y) - (s2y * 0.1f - p2v.y);
        const float dz = (s1z * 0.1f - qp.z) - (s2z * 0.1f - p2v.z);
        if (lane == 0) acc += fabsf(dx) + fabsf(dy) + fabsf(dz);
    }

    if (lane == 0 && acc != 0.0f)
        atomicAdd(out, acc * (1.0f / (float)(NB * NPTS * 3)));
}

// ---------------- round-2 fallback (O(N^2), verified) ----------------
constexpr int FB_WPB = 8;
constexpr int FB_BLOCK = QPB * FB_WPB;  // 512
constexpr int CHUNK = NPTS / FB_WPB;

__global__ void prep_pack(const float* __restrict__ p, float4* __restrict__ w) {
    const int i = blockIdx.x * blockDim.x + threadIdx.x;
    if (i < NB * NPTS) {
        const float x = p[3 * i], y = p[3 * i + 1], z = p[3 * i + 2];
        w[i] = make_float4(x, y, z, fmaf(x, x, fmaf(y, y, z * z)));
    }
}

__global__ __launch_bounds__(FB_BLOCK, 2)
void knn_lap(const float4* __restrict__ w1, const float* __restrict__ p2,
             float* __restrict__ out)
{
    __shared__ int mv[FB_WPB * KNN * QPB];
    const int batch = blockIdx.x >> 7;
    const int qbase = (blockIdx.x & 127) << 6;
    const int lane  = threadIdx.x & 63;
    const int wv    = __builtin_amdgcn_readfirstlane(threadIdx.x >> 6);
    const int query = qbase + lane;
    const float4* Wb = w1 + batch * NPTS;
    const float4 qp = Wb[query];
    const float m2x = -2.0f * qp.x, m2y = -2.0f * qp.y, m2z = -2.0f * qp.z;
    const float q2 = qp.w;
    const int IMAX = 0x7FFFFFFF;
    int l[KNN];
#pragma unroll
    for (int k = 0; k < KNN; ++k) l[k] = IMAX;
    const int c0 = wv * CHUNK;
    const float4* cand = Wb + c0;
#pragma unroll 4
    for (int i = 0; i < CHUNK; i += 2) {
        const float4 ca = cand[i];
        const float4 cb = cand[i + 1];
        const int ja = c0 + i, jb = ja + 1;
        const float da = fmaf(m2x, ca.x, fmaf(m2y, ca.y, fmaf(m2z, ca.z, ca.w + q2)));
        const float db = fmaf(m2x, cb.x, fmaf(m2y, cb.y, fmaf(m2z, cb.z, cb.w + q2)));
        int ka = (__float_as_int(da) & MASK13) | ja;
        int kb = (__float_as_int(db) & MASK13) | jb;
        ka = (ja == query) ? IMAX : ka;
        kb = (jb == query) ? IMAX : kb;
        ins2(l, ka, kb);
    }
#pragma unroll
    for (int k = 0; k < KNN; ++k) mv[(wv * KNN + k) * QPB + lane] = l[k];
    __syncthreads();
    if (threadIdx.x < QPB) {
        int m[KNN];
#pragma unroll
        for (int k = 0; k < KNN; ++k) m[k] = IMAX;
#pragma unroll
        for (int e = 0; e < FB_WPB; ++e) {
            int p[KNN];
#pragma unroll
            for (int k = 0; k < KNN; ++k) p[k] = mv[(e * KNN + k) * QPB + lane];
            merge_sorted(m, p);
        }
        const float* P2b = p2 + (size_t)batch * NPTS * 3;
        float s1x = 0, s1y = 0, s1z = 0, s2x = 0, s2y = 0, s2z = 0;
#pragma unroll
        for (int k = 0; k < KNN; ++k) {
            const int j = m[k] & (NPTS - 1);
            const float4 c = Wb[j];
            s1x += c.x; s1y += c.y; s1z += c.z;
            s2x += P2b[3 * j + 0]; s2y += P2b[3 * j + 1]; s2z += P2b[3 * j + 2];
        }
        const int q = qbase + threadIdx.x;
        const float p2x = P2b[3 * q + 0], p2y = P2b[3 * q + 1], p2z = P2b[3 * q + 2];
        const float dx = (s1x * 0.1f - qp.x) - (s2x * 0.1f - p2x);
        const float dy = (s1y * 0.1f - qp.y) - (s2y * 0.1f - p2y);
        const float dz = (s1z * 0.1f - qp.z) - (s2z * 0.1f - p2z);
        float v = fabsf(dx) + fabsf(dy) + fabsf(dz);
#pragma unroll
        for (int off = 32; off >= 1; off >>= 1) v += __shfl_down(v, off);
        if (threadIdx.x == 0)
            atomicAdd(out, v * (1.0f / (float)(NB * NPTS * 3)));
    }
}

// ---------------- launcher ----------------
extern "C" void kernel_launch(void* const* d_in, const int* in_sizes, int n_in,
                              void* d_out, int out_size, void* d_ws, size_t ws_size,
                              hipStream_t stream) {
    const float* p1 = (const float*)d_in[0];
    const float* p2 = (const float*)d_in[1];
    float* out = (float*)d_out;

    size_t off = 0;
    float4* w       = (float4*)d_ws;               off += (size_t)NB * NPTS * 16;
    int*    hist    = (int*)((char*)d_ws + off);   off += (size_t)NB * NC * 4;
    int*    starts  = (int*)((char*)d_ws + off);   off += (size_t)NB * (NC + 1) * 4 + 8;
    int*    cellof  = (int*)((char*)d_ws + off);   off += (size_t)NB * NPTS * 4;
    float4* wsorted = (float4*)((char*)d_ws + off); off += (size_t)NB * NPTS * 16;
    float4* p2s     = (float4*)((char*)d_ws + off); off += (size_t)NB * NPTS * 16;
    int*    nfail   = (int*)((char*)d_ws + off);   off += 16;
    int*    worklist= (int*)((char*)d_ws + off);   off += (size_t)NB * NPTS * 4;

    if (ws_size < off) {  // fallback: round-2 brute force
        hipMemsetAsync(out, 0, sizeof(float), stream);
        prep_pack<<<(NB * NPTS + 255) / 256, 256, 0, stream>>>(p1, w);
        knn_lap<<<NB * (NPTS / QPB), FB_BLOCK, 0, stream>>>(w, p2, out);
        return;
    }

    hipMemsetAsync(hist, 0, (size_t)NB * NC * 4, stream);
    pack_bin<<<(NB * NPTS + 255) / 256, 256, 0, stream>>>(p1, w, hist, cellof,
                                                          out, nfail);
    scan_cells<<<NB, 1024, 0, stream>>>(hist, starts);
    scatter_all<<<(NB * NPTS + 255) / 256, 256, 0, stream>>>(cellof, starts, hist,
                                                             w, p2, wsorted, p2s);
    phase1<<<NB * (NPTS / QPB), BLOCK, 0, stream>>>(wsorted, p2s, starts, out,
                                                    nfail, worklist);
    phase2<<<P2GRID, P2BLK, 0, stream>>>(wsorted, p2s, nfail, worklist, out);
}